// Round 1
// baseline (2903.683 us; speedup 1.0000x reference)
//
#include <hip/hip_runtime.h>
#include <math.h>
#include <stdint.h>

#define DEV __device__ __forceinline__

// ---------------- problem constants ----------------
constexpr int Bz = 16, T = 512, D = 1024, H = 16, HS = 64, Lx = 4, DFF = 4096, NCn = 3;
constexpr int BT = Bz * T;  // 8192

typedef __attribute__((ext_vector_type(8))) short v8s;   // 8 x bf16 (4 VGPRs)
typedef __attribute__((ext_vector_type(4))) float v4f;   // MFMA accum

// ---------------- helpers ----------------
DEV uint16_t f2bf(float f) {            // round-to-nearest-even fp32 -> bf16
  uint32_t u = __float_as_uint(f);
  u += 0x7fff + ((u >> 16) & 1);
  return (uint16_t)(u >> 16);
}
DEV float bf2f(uint16_t v) { return __uint_as_float(((uint32_t)v) << 16); }

DEV void async_copy16(const void* g, void* l) {
  // lane-uniform LDS base; HW deposits at base + lane*16
  __builtin_amdgcn_global_load_lds(
      (const __attribute__((address_space(1))) uint32_t*)g,
      (__attribute__((address_space(3))) uint32_t*)l, 16, 0, 0);
}

// ---------------- transpose + cast: in fp32 [R,C] -> out bf16 [C,R], batched over z ----
__global__ void transpose_cast_kernel(const float* __restrict__ in, uint16_t* __restrict__ out,
                                      int R, int C) {
  __shared__ float tile[32][33];
  long bo = (long)blockIdx.z * R * C;
  in += bo; out += bo;
  int c0 = blockIdx.x * 32, r0 = blockIdx.y * 32;
  int tx = threadIdx.x, ty = threadIdx.y;  // 32 x 8
  for (int i = 0; i < 32; i += 8)
    tile[ty + i][tx] = in[(long)(r0 + ty + i) * C + (c0 + tx)];
  __syncthreads();
  for (int i = 0; i < 32; i += 8)
    out[(long)(c0 + ty + i) * R + (r0 + tx)] = f2bf(tile[tx][ty + i]);
}

// ---------------- embedding: h[b,t,:] = tok[x[b,t],:] + pos[t,:] ----------------
__global__ void embed_kernel(const int* __restrict__ x, const float* __restrict__ tok,
                             const float* __restrict__ pos, float* __restrict__ h) {
  int row = blockIdx.x;              // b*T + t
  int t = row & (T - 1);
  int id = x[row];
  const float4* tr = (const float4*)(tok + (long)id * D);
  const float4* pr = (const float4*)(pos + (long)t * D);
  float4* hr = (float4*)(h + (long)row * D);
  int i = threadIdx.x;               // 256 threads * 4 floats = 1024
  float4 a = tr[i], b = pr[i];
  hr[i] = make_float4(a.x + b.x, a.y + b.y, a.z + b.z, a.w + b.w);
}

// ---------------- layernorm over D=1024; one block per row ----------------
template <bool OUT_BF16>
__global__ void ln_kernel(const float* __restrict__ in, const float* __restrict__ g,
                          const float* __restrict__ b, void* __restrict__ out) {
  int row = blockIdx.x;
  int i = threadIdx.x;  // 256
  const float4* xr = (const float4*)(in + (long)row * D);
  float4 v = xr[i];
  float s = v.x + v.y + v.z + v.w;
  float s2 = v.x * v.x + v.y * v.y + v.z * v.z + v.w * v.w;
  for (int off = 32; off; off >>= 1) { s += __shfl_down(s, off); s2 += __shfl_down(s2, off); }
  __shared__ float sh1[4], sh2[4];
  int wid = i >> 6, lane = i & 63;
  if (lane == 0) { sh1[wid] = s; sh2[wid] = s2; }
  __syncthreads();
  s = sh1[0] + sh1[1] + sh1[2] + sh1[3];
  s2 = sh2[0] + sh2[1] + sh2[2] + sh2[3];
  float mu = s * (1.0f / D);
  float rstd = rsqrtf(s2 * (1.0f / D) - mu * mu + 1e-5f);
  float4 gv = ((const float4*)g)[i];
  float4 bv = ((const float4*)b)[i];
  float o0 = (v.x - mu) * rstd * gv.x + bv.x;
  float o1 = (v.y - mu) * rstd * gv.y + bv.y;
  float o2 = (v.z - mu) * rstd * gv.z + bv.z;
  float o3 = (v.w - mu) * rstd * gv.w + bv.w;
  if constexpr (OUT_BF16) {
    uint16_t* orow = (uint16_t*)out + (long)row * D;
    orow[4 * i + 0] = f2bf(o0); orow[4 * i + 1] = f2bf(o1);
    orow[4 * i + 2] = f2bf(o2); orow[4 * i + 3] = f2bf(o3);
  } else {
    ((float4*)((float*)out + (long)row * D))[i] = make_float4(o0, o1, o2, o3);
  }
}

// ---------------- in-place scaled softmax over rows of 512 bf16 ----------------
__global__ void softmax_kernel(uint16_t* __restrict__ S) {
  long row = blockIdx.x;
  uint32_t* r = (uint32_t*)(S + row * (long)T);
  int i = threadIdx.x;  // 256 threads, 2 elems each
  uint32_t u = r[i];
  float a = __uint_as_float(u << 16) * 0.125f;          // * HS^-0.5
  float b = __uint_as_float(u & 0xffff0000u) * 0.125f;
  float m = fmaxf(a, b);
  for (int off = 32; off; off >>= 1) m = fmaxf(m, __shfl_down(m, off));
  __shared__ float sh[4], sh2[4];
  int wid = i >> 6, lane = i & 63;
  if (lane == 0) sh[wid] = m;
  __syncthreads();
  m = fmaxf(fmaxf(sh[0], sh[1]), fmaxf(sh[2], sh[3]));
  float ea = expf(a - m), eb = expf(b - m);
  float s = ea + eb;
  for (int off = 32; off; off >>= 1) s += __shfl_down(s, off);
  if (lane == 0) sh2[wid] = s;
  __syncthreads();
  float inv = 1.0f / (sh2[0] + sh2[1] + sh2[2] + sh2[3]);
  r[i] = (uint32_t)f2bf(ea * inv) | ((uint32_t)f2bf(eb * inv) << 16);
}

// ---------------- the MFMA GEMM ----------------
// C[M,N] = A[M,K] * Bt[N,K]^T ; A,Bt bf16 row-major; fp32 accum. Batched via blockIdx.z.
enum { MQK = 0, MVT = 1, MBF = 2, MO = 3, MRES = 4, MGELU = 5 };

template <int BM, int BN, int WGM, int WGN, int MODE>
__global__ void gemm_kernel(const uint16_t* __restrict__ A, const uint16_t* __restrict__ Bt,
                            int M, int N, int K,
                            long strideA, long strideB, long strideC,
                            const float* __restrict__ bias, void* __restrict__ Cout) {
  constexpr int BK = 32;
  constexpr int WM = BM / WGM, WN = BN / WGN;
  constexpr int TM = WM / 16, TN = WN / 16;
  __shared__ __align__(16) uint16_t As[BM * BK];
  __shared__ __align__(16) uint16_t Bs[BN * BK];
  int batch = blockIdx.z;
  A += (long)batch * strideA;
  Bt += (long)batch * strideB;
  int bn0 = blockIdx.x * BN, bm0 = blockIdx.y * BM;
  int tid = threadIdx.x, wid = tid >> 6, lane = tid & 63;
  int wm = wid / WGN, wn = wid % WGN;
  v4f acc[TM][TN] = {};
  const int laneRow = lane >> 2;            // 16 rows per 1 KiB chunk
  const int laneB = (lane & 3) * 16;        // 4 x 16B per row (row = 64B = 32 bf16)

  for (int k0 = 0; k0 < K; k0 += BK) {
    __syncthreads();  // previous iter done reading LDS
    for (int c = wid; c < BM / 16; c += 4) {
      int row = bm0 + c * 16 + laneRow;
      const char* g = (const char*)(A + (long)row * K + k0) + laneB;
      async_copy16(g, (char*)As + c * 1024);
    }
    for (int c = wid; c < BN / 16; c += 4) {
      int col = bn0 + c * 16 + laneRow;
      const char* g = (const char*)(Bt + (long)col * K + k0) + laneB;
      async_copy16(g, (char*)Bs + c * 1024);
    }
    __syncthreads();  // drains vmcnt -> staged tiles visible

    int kq = (lane >> 4) * 8;
    v8s af[TM], bfr[TN];
#pragma unroll
    for (int i = 0; i < TM; i++) {
      int r = wm * WM + i * 16 + (lane & 15);
      af[i] = *(const v8s*)&As[r * BK + kq];
    }
#pragma unroll
    for (int j = 0; j < TN; j++) {
      int c = wn * WN + j * 16 + (lane & 15);
      bfr[j] = *(const v8s*)&Bs[c * BK + kq];
    }
#pragma unroll
    for (int i = 0; i < TM; i++)
#pragma unroll
      for (int j = 0; j < TN; j++)
        acc[i][j] = __builtin_amdgcn_mfma_f32_16x16x32_bf16(af[i], bfr[j], acc[i][j], 0, 0, 0);
  }

  // epilogue: C/D layout col=lane&15, row=(lane>>4)*4+r
#pragma unroll
  for (int i = 0; i < TM; i++) {
    int row0 = bm0 + wm * WM + i * 16 + (lane >> 4) * 4;
#pragma unroll
    for (int j = 0; j < TN; j++) {
      int col = bn0 + wn * WN + j * 16 + (lane & 15);
#pragma unroll
      for (int r = 0; r < 4; r++) {
        int row = row0 + r;
        float val = acc[i][j][r];
        if constexpr (MODE == MQK) {            // q/k: [b,h,t,e]
          int b = row >> 9, t = row & 511, hh = col >> 6, e = col & 63;
          ((uint16_t*)Cout)[((long)(b * H + hh) * T + t) * HS + e] = f2bf(val);
        } else if constexpr (MODE == MVT) {     // v transposed: [b,h,e,t]
          int b = row >> 9, t = row & 511, hh = col >> 6, e = col & 63;
          ((uint16_t*)Cout)[((long)(b * H + hh) * HS + e) * T + t] = f2bf(val);
        } else if constexpr (MODE == MBF) {     // plain bf16, batched
          ((uint16_t*)Cout)[(long)batch * strideC + (long)row * N + col] = f2bf(val);
        } else if constexpr (MODE == MO) {      // attn out: [b,t,h,e]; batch=b*H+h
          int b = batch >> 4, hh = batch & 15;
          ((uint16_t*)Cout)[((long)(b * T + row) * H + hh) * HS + col] = f2bf(val);
        } else if constexpr (MODE == MRES) {    // h += acc + bias (fp32 residual)
          ((float*)Cout)[(long)row * N + col] += val + bias[col];
        } else if constexpr (MODE == MGELU) {   // bf16 gelu(acc + bias)
          float xg = val + bias[col];
          float gl = 0.5f * xg * (1.0f + erff(xg * 0.70710678118f));
          ((uint16_t*)Cout)[(long)row * N + col] = f2bf(gl);
        }
      }
    }
  }
}

// ---------------- logits: out[b,c] = bout[c] + sum_i h[b,i] * Wout[i,c] ----------------
__global__ void logits_init(const float* __restrict__ bout, float* __restrict__ out) {
  int i = threadIdx.x;
  if (i < Bz * NCn) out[i] = bout[i % NCn];
}
__global__ void logits_kernel(const float* __restrict__ hf, const float* __restrict__ Wout,
                              float* __restrict__ out) {
  int b = blockIdx.y, c = blockIdx.z;
  long base = (long)blockIdx.x * 8192;  // T*D / 64 chunks
  const float* hv = hf + (long)b * T * D + base;
  const float* w = Wout + base * NCn + c;
  float s = 0.f;
  for (int i = threadIdx.x; i < 8192; i += 256) s += hv[i] * w[(long)i * NCn];
  for (int off = 32; off; off >>= 1) s += __shfl_down(s, off);
  __shared__ float sh[4];
  int wid = threadIdx.x >> 6, lane = threadIdx.x & 63;
  if (lane == 0) sh[wid] = s;
  __syncthreads();
  if (threadIdx.x == 0) atomicAdd(out + b * NCn + c, sh[0] + sh[1] + sh[2] + sh[3]);
}

// ---------------- host ----------------
extern "C" void kernel_launch(void* const* d_in, const int* in_sizes, int n_in,
                              void* d_out, int out_size, void* d_ws, size_t ws_size,
                              hipStream_t stream) {
  const int* x = (const int*)d_in[0];
  const float* tok = (const float*)d_in[1];
  const float* pos = (const float*)d_in[2];
  const float* Wq = (const float*)d_in[3];
  const float* Wk = (const float*)d_in[4];
  const float* Wv = (const float*)d_in[5];
  const float* Wproj = (const float*)d_in[6];
  const float* bproj = (const float*)d_in[7];
  const float* ln1g = (const float*)d_in[8];
  const float* ln1b = (const float*)d_in[9];
  const float* ln2g = (const float*)d_in[10];
  const float* ln2b = (const float*)d_in[11];
  const float* W1 = (const float*)d_in[12];
  const float* b1 = (const float*)d_in[13];
  const float* W2 = (const float*)d_in[14];
  const float* b2 = (const float*)d_in[15];
  const float* lnfg = (const float*)d_in[16];
  const float* lnfb = (const float*)d_in[17];
  const float* Wout = (const float*)d_in[18];
  const float* bout = (const float*)d_in[19];
  float* out = (float*)d_out;

  // workspace layout
  char* ws = (char*)d_ws;
  size_t off = 0;
  auto alloc = [&](size_t bytes) { char* p = ws + off; off += (bytes + 255) & ~(size_t)255; return p; };
  uint16_t* wqT = (uint16_t*)alloc((size_t)Lx * D * D * 2);
  uint16_t* wkT = (uint16_t*)alloc((size_t)Lx * D * D * 2);
  uint16_t* wvT = (uint16_t*)alloc((size_t)Lx * D * D * 2);
  uint16_t* wpT = (uint16_t*)alloc((size_t)Lx * D * D * 2);
  uint16_t* w1T = (uint16_t*)alloc((size_t)Lx * D * DFF * 2);
  uint16_t* w2T = (uint16_t*)alloc((size_t)Lx * D * DFF * 2);
  float* h = (float*)alloc((size_t)BT * D * 4);
  uint16_t* z = (uint16_t*)alloc((size_t)BT * D * 2);
  uint16_t* q = (uint16_t*)alloc((size_t)Bz * H * T * HS * 2);
  uint16_t* kb = (uint16_t*)alloc((size_t)Bz * H * T * HS * 2);
  uint16_t* vt = (uint16_t*)alloc((size_t)Bz * H * T * HS * 2);
  uint16_t* S = (uint16_t*)alloc((size_t)Bz * H * T * T * 2);
  uint16_t* o = (uint16_t*)alloc((size_t)BT * D * 2);
  uint16_t* a1 = (uint16_t*)alloc((size_t)BT * DFF * 2);
  (void)ws_size; (void)in_sizes; (void)n_in; (void)out_size;

  dim3 tb(32, 8);
  // weights -> bf16, transposed (B^T layout: [N][K])
  transpose_cast_kernel<<<dim3(HS / 32, D / 32, Lx * H), tb, 0, stream>>>(Wq, wqT, D, HS);
  transpose_cast_kernel<<<dim3(HS / 32, D / 32, Lx * H), tb, 0, stream>>>(Wk, wkT, D, HS);
  transpose_cast_kernel<<<dim3(HS / 32, D / 32, Lx * H), tb, 0, stream>>>(Wv, wvT, D, HS);
  transpose_cast_kernel<<<dim3(D / 32, D / 32, Lx), tb, 0, stream>>>(Wproj, wpT, D, D);
  transpose_cast_kernel<<<dim3(DFF / 32, D / 32, Lx), tb, 0, stream>>>(W1, w1T, D, DFF);
  transpose_cast_kernel<<<dim3(D / 32, DFF / 32, Lx), tb, 0, stream>>>(W2, w2T, DFF, D);

  embed_kernel<<<BT, 256, 0, stream>>>(x, tok, pos, h);

  for (int l = 0; l < Lx; l++) {
    const uint16_t* wq_l = wqT + (size_t)l * D * D;
    const uint16_t* wk_l = wkT + (size_t)l * D * D;
    const uint16_t* wv_l = wvT + (size_t)l * D * D;
    const uint16_t* wp_l = wpT + (size_t)l * D * D;
    const uint16_t* w1_l = w1T + (size_t)l * D * DFF;
    const uint16_t* w2_l = w2T + (size_t)l * D * DFF;

    ln_kernel<true><<<BT, 256, 0, stream>>>(h, ln1g + l * D, ln1b + l * D, z);

    gemm_kernel<128, 128, 2, 2, MQK><<<dim3(D / 128, BT / 128, 1), 256, 0, stream>>>(
        z, wq_l, BT, D, D, 0, 0, 0, nullptr, q);
    gemm_kernel<128, 128, 2, 2, MQK><<<dim3(D / 128, BT / 128, 1), 256, 0, stream>>>(
        z, wk_l, BT, D, D, 0, 0, 0, nullptr, kb);
    gemm_kernel<128, 128, 2, 2, MVT><<<dim3(D / 128, BT / 128, 1), 256, 0, stream>>>(
        z, wv_l, BT, D, D, 0, 0, 0, nullptr, vt);

    // S = q @ k^T  (per b,h): M=N=512, K=64
    gemm_kernel<128, 128, 2, 2, MBF><<<dim3(T / 128, T / 128, Bz * H), 256, 0, stream>>>(
        q, kb, T, T, HS, (long)T * HS, (long)T * HS, (long)T * T, nullptr, S);

    softmax_kernel<<<(long)Bz * H * T, 256, 0, stream>>>(S);

    // O = P @ V : M=512, N=64, K=512
    gemm_kernel<128, 64, 4, 1, MO><<<dim3(1, T / 128, Bz * H), 256, 0, stream>>>(
        S, vt, T, HS, T, (long)T * T, (long)HS * T, 0, nullptr, o);

    // h += o @ Wproj + bproj
    gemm_kernel<128, 128, 2, 2, MRES><<<dim3(D / 128, BT / 128, 1), 256, 0, stream>>>(
        o, wp_l, BT, D, D, 0, 0, 0, bproj + l * D, h);

    ln_kernel<true><<<BT, 256, 0, stream>>>(h, ln2g + l * D, ln2b + l * D, z);

    // a1 = gelu(z @ W1 + b1)
    gemm_kernel<128, 128, 2, 2, MGELU><<<dim3(DFF / 128, BT / 128, 1), 256, 0, stream>>>(
        z, w1_l, BT, DFF, D, 0, 0, 0, b1 + l * DFF, a1);

    // h += a1 @ W2 + b2
    gemm_kernel<128, 128, 2, 2, MRES><<<dim3(D / 128, BT / 128, 1), 256, 0, stream>>>(
        a1, w2_l, BT, D, DFF, 0, 0, 0, b2 + l * D, h);
  }

  // final LN in-place (fp32), then logits
  ln_kernel<false><<<BT, 256, 0, stream>>>(h, lnfg, lnfb, h);
  logits_init<<<1, 64, 0, stream>>>(bout, out);
  logits_kernel<<<dim3(64, Bz, NCn), 256, 0, stream>>>(h, Wout, out);
}

// Round 2
// 2591.083 us; speedup vs baseline: 1.1206x; 1.1206x over previous
//
#include <hip/hip_runtime.h>
#include <math.h>
#include <stdint.h>

#define DEV __device__ __forceinline__

// ---------------- problem constants ----------------
constexpr int Bz = 16, T = 512, D = 1024, H = 16, HS = 64, Lx = 4, DFF = 4096, NCn = 3;
constexpr int BT = Bz * T;  // 8192
constexpr long QSZ = (long)Bz * H * T * HS;  // elements per q/k/v tensor

typedef __attribute__((ext_vector_type(8))) short v8s;   // 8 x bf16 (4 VGPRs)
typedef __attribute__((ext_vector_type(4))) float v4f;   // MFMA accum

// ---------------- helpers ----------------
DEV uint16_t f2bf(float f) {            // round-to-nearest-even fp32 -> bf16
  uint32_t u = __float_as_uint(f);
  u += 0x7fff + ((u >> 16) & 1);
  return (uint16_t)(u >> 16);
}

DEV void async_copy16(const void* g, void* l) {
  // LDS base must be wave-uniform; HW deposits at base + lane*16
  __builtin_amdgcn_global_load_lds(
      (const __attribute__((address_space(1))) uint32_t*)g,
      (__attribute__((address_space(3))) uint32_t*)l, 16, 0, 0);
}

// ---- transpose + cast: in fp32 [R,C] batched z -> out bf16 [C,R] at (z/zdiv)*s1+(z%zdiv)*s2
__global__ void transpose_cast_kernel(const float* __restrict__ in, uint16_t* __restrict__ out,
                                      int R, int C, long s1, long s2, int zdiv) {
  __shared__ float tile[32][33];
  int zz = blockIdx.z;
  in += (long)zz * R * C;
  out += (long)(zz / zdiv) * s1 + (long)(zz % zdiv) * s2;
  int c0 = blockIdx.x * 32, r0 = blockIdx.y * 32;
  int tx = threadIdx.x, ty = threadIdx.y;  // 32 x 8
  for (int i = 0; i < 32; i += 8)
    tile[ty + i][tx] = in[(long)(r0 + ty + i) * C + (c0 + tx)];
  __syncthreads();
  for (int i = 0; i < 32; i += 8)
    out[(long)(c0 + ty + i) * R + (r0 + tx)] = f2bf(tile[tx][ty + i]);
}

// ---------------- embedding: h[b,t,:] = tok[x[b,t],:] + pos[t,:] ----------------
__global__ void embed_kernel(const int* __restrict__ x, const float* __restrict__ tok,
                             const float* __restrict__ pos, float* __restrict__ h) {
  int row = blockIdx.x;              // b*T + t
  int t = row & (T - 1);
  int id = x[row];
  const float4* tr = (const float4*)(tok + (long)id * D);
  const float4* pr = (const float4*)(pos + (long)t * D);
  float4* hr = (float4*)(h + (long)row * D);
  int i = threadIdx.x;               // 256 threads * 4 floats = 1024
  float4 a = tr[i], b = pr[i];
  hr[i] = make_float4(a.x + b.x, a.y + b.y, a.z + b.z, a.w + b.w);
}

// ---------------- layernorm over D=1024; one block per row ----------------
template <bool OUT_BF16>
__global__ void ln_kernel(const float* __restrict__ in, const float* __restrict__ g,
                          const float* __restrict__ b, void* __restrict__ out) {
  int row = blockIdx.x;
  int i = threadIdx.x;  // 256
  const float4* xr = (const float4*)(in + (long)row * D);
  float4 v = xr[i];
  float s = v.x + v.y + v.z + v.w;
  float s2 = v.x * v.x + v.y * v.y + v.z * v.z + v.w * v.w;
  for (int off = 32; off; off >>= 1) { s += __shfl_down(s, off); s2 += __shfl_down(s2, off); }
  __shared__ float sh1[4], sh2[4];
  int wid = i >> 6, lane = i & 63;
  if (lane == 0) { sh1[wid] = s; sh2[wid] = s2; }
  __syncthreads();
  s = sh1[0] + sh1[1] + sh1[2] + sh1[3];
  s2 = sh2[0] + sh2[1] + sh2[2] + sh2[3];
  float mu = s * (1.0f / D);
  float rstd = rsqrtf(s2 * (1.0f / D) - mu * mu + 1e-5f);
  float4 gv = ((const float4*)g)[i];
  float4 bv = ((const float4*)b)[i];
  float o0 = (v.x - mu) * rstd * gv.x + bv.x;
  float o1 = (v.y - mu) * rstd * gv.y + bv.y;
  float o2 = (v.z - mu) * rstd * gv.z + bv.z;
  float o3 = (v.w - mu) * rstd * gv.w + bv.w;
  if constexpr (OUT_BF16) {
    uint16_t* orow = (uint16_t*)out + (long)row * D;
    orow[4 * i + 0] = f2bf(o0); orow[4 * i + 1] = f2bf(o1);
    orow[4 * i + 2] = f2bf(o2); orow[4 * i + 3] = f2bf(o3);
  } else {
    ((float4*)((float*)out + (long)row * D))[i] = make_float4(o0, o1, o2, o3);
  }
}

// ---------- in-place scaled softmax: one wave per row of 512 bf16 (no LDS/barriers) ----------
__global__ void softmax_kernel(uint16_t* __restrict__ S) {
  int wid = threadIdx.x >> 6, lane = threadIdx.x & 63;
  long row = (long)blockIdx.x * 4 + wid;
  uint4* p = (uint4*)(S + row * T) + lane;   // 8 bf16 per lane
  uint4 u = *p;
  uint32_t w[4] = {u.x, u.y, u.z, u.w};
  float lo[4], hi[4];
  float m = -1e30f;
#pragma unroll
  for (int i = 0; i < 4; i++) {
    lo[i] = __uint_as_float(w[i] << 16) * 0.125f;          // * HS^-0.5
    hi[i] = __uint_as_float(w[i] & 0xffff0000u) * 0.125f;
    m = fmaxf(m, fmaxf(lo[i], hi[i]));
  }
  for (int off = 32; off; off >>= 1) m = fmaxf(m, __shfl_xor(m, off));
  float s = 0.f;
#pragma unroll
  for (int i = 0; i < 4; i++) {
    lo[i] = expf(lo[i] - m); hi[i] = expf(hi[i] - m);
    s += lo[i] + hi[i];
  }
  for (int off = 32; off; off >>= 1) s += __shfl_xor(s, off);
  float inv = 1.0f / s;
  uint4 o;
  uint32_t* ow = (uint32_t*)&o;
#pragma unroll
  for (int i = 0; i < 4; i++)
    ow[i] = (uint32_t)f2bf(lo[i] * inv) | ((uint32_t)f2bf(hi[i] * inv) << 16);
  *p = o;
}

// ---------------- the MFMA GEMM ----------------
// C[M,N] = A[M,K] * Bt[N,K]^T ; bf16, fp32 accum. Grid: x = M-tiles (fastest ->
// column-major traversal: XCD c owns rows ≡ c mod 8, B-stripe stays hot in its L2).
// MATOMIC: blockIdx.z = K-split index, K = chunk length, lda/ldb = true leading dims.
enum { MQKV = 0, MBF = 1, MO = 2, MATOMIC = 3, MGELU = 4 };

template <int BM, int BN, int WGM, int WGN, int MODE>
__global__ void gemm_kernel(const uint16_t* __restrict__ A, const uint16_t* __restrict__ Bt,
                            int M, int N, int K, int lda, int ldb,
                            long strideA, long strideB, long strideC,
                            const float* __restrict__ bias, void* __restrict__ Cout) {
  constexpr int BK = 32;
  constexpr int WM = BM / WGM, WN = BN / WGN;
  constexpr int TM = WM / 16, TN = WN / 16;
  __shared__ __align__(16) uint16_t As[BM * BK];
  __shared__ __align__(16) uint16_t Bs[BN * BK];
  int kz = 0, batch = 0;
  if constexpr (MODE == MATOMIC) kz = blockIdx.z; else batch = blockIdx.z;
  A += (long)batch * strideA;
  Bt += (long)batch * strideB;
  const int kb0 = kz * K;
  int bm0 = blockIdx.x * BM, bn0 = blockIdx.y * BN;
  int tid = threadIdx.x, wid = tid >> 6, lane = tid & 63;
  int wm = wid / WGN, wn = wid % WGN;
  v4f acc[TM][TN] = {};

  // staging: lane quad permuted (XOR swizzle) on the GLOBAL side; LDS dst stays i*16
  const int laneRow = lane >> 2;                          // 16 rows per 1 KiB chunk
  const int laneB = ((lane & 3) ^ ((laneRow >> 1) & 3)) * 16;
  // fragment read: same XOR applied -> 2 lanes/bank-quad (free)
  const int rl = lane & 15;
  const int cx16 = (rl * 4 + ((lane >> 4) ^ ((rl >> 1) & 3))) * 16;  // byte offset in 1 KiB block

  for (int k0 = kb0; k0 < kb0 + K; k0 += BK) {
    __syncthreads();  // previous iter done reading LDS
    for (int c = wid; c < BM / 16; c += 4) {
      int row = bm0 + c * 16 + laneRow;
      async_copy16((const char*)(A + (long)row * lda + k0) + laneB, (char*)As + c * 1024);
    }
    for (int c = wid; c < BN / 16; c += 4) {
      int col = bn0 + c * 16 + laneRow;
      async_copy16((const char*)(Bt + (long)col * ldb + k0) + laneB, (char*)Bs + c * 1024);
    }
    __syncthreads();  // drains vmcnt -> staged tiles visible

    v8s af[TM], bfr[TN];
#pragma unroll
    for (int i = 0; i < TM; i++)
      af[i] = *(const v8s*)((const char*)As + (wm * (WM / 16) + i) * 1024 + cx16);
#pragma unroll
    for (int j = 0; j < TN; j++)
      bfr[j] = *(const v8s*)((const char*)Bs + (wn * (WN / 16) + j) * 1024 + cx16);
#pragma unroll
    for (int i = 0; i < TM; i++)
#pragma unroll
      for (int j = 0; j < TN; j++)
        acc[i][j] = __builtin_amdgcn_mfma_f32_16x16x32_bf16(af[i], bfr[j], acc[i][j], 0, 0, 0);
  }

  // epilogue: C/D layout col=lane&15, row=(lane>>4)*4+r
#pragma unroll
  for (int i = 0; i < TM; i++) {
    int row0 = bm0 + wm * WM + i * 16 + (lane >> 4) * 4;
#pragma unroll
    for (int j = 0; j < TN; j++) {
      int col = bn0 + wn * WN + j * 16 + (lane & 15);
#pragma unroll
      for (int r = 0; r < 4; r++) {
        int row = row0 + r;
        float val = acc[i][j][r];
        if constexpr (MODE == MQKV) {          // fused qkv scatter
          int sel = col >> 10, c = col & 1023;
          int hh = c >> 6, e = c & 63;
          int b = row >> 9, t = row & 511;
          long idx = (sel < 2) ? (((long)(b * H + hh) * T + t) * HS + e)
                               : (((long)(b * H + hh) * HS + e) * T + t);  // v transposed
          ((uint16_t*)Cout)[(long)sel * QSZ + idx] = f2bf(val);
        } else if constexpr (MODE == MBF) {    // plain bf16, batched (scores)
          ((uint16_t*)Cout)[(long)batch * strideC + (long)row * N + col] = f2bf(val);
        } else if constexpr (MODE == MO) {     // attn out: [b,t,h,e]; batch=b*H+h
          int b = batch >> 4, hh = batch & 15;
          ((uint16_t*)Cout)[((long)(b * T + row) * H + hh) * HS + col] = f2bf(val);
        } else if constexpr (MODE == MATOMIC) {  // h += partial (+bias once)
          float add = val + ((kz == 0) ? bias[col] : 0.f);
          atomicAdd(&((float*)Cout)[(long)row * N + col], add);
        } else if constexpr (MODE == MGELU) {  // bf16 gelu(acc + bias)
          float xg = val + bias[col];
          float gl = 0.5f * xg * (1.0f + erff(xg * 0.70710678118f));
          ((uint16_t*)Cout)[(long)row * N + col] = f2bf(gl);
        }
      }
    }
  }
}

// ---------------- logits: out[b,c] = bout[c] + sum_i h[b,i] * Wout[i,c] ----------------
__global__ void logits_init(const float* __restrict__ bout, float* __restrict__ out) {
  int i = threadIdx.x;
  if (i < Bz * NCn) out[i] = bout[i % NCn];
}
__global__ void logits_kernel(const float* __restrict__ hf, const float* __restrict__ Wout,
                              float* __restrict__ out) {
  int b = blockIdx.y, c = blockIdx.z;
  long base = (long)blockIdx.x * 8192;  // T*D / 64 chunks
  const float* hv = hf + (long)b * T * D + base;
  const float* w = Wout + base * NCn + c;
  float s = 0.f;
  for (int i = threadIdx.x; i < 8192; i += 256) s += hv[i] * w[(long)i * NCn];
  for (int off = 32; off; off >>= 1) s += __shfl_down(s, off);
  __shared__ float sh[4];
  int wid = threadIdx.x >> 6, lane = threadIdx.x & 63;
  if (lane == 0) sh[wid] = s;
  __syncthreads();
  if (threadIdx.x == 0) atomicAdd(out + b * NCn + c, sh[0] + sh[1] + sh[2] + sh[3]);
}

// ---------------- host ----------------
extern "C" void kernel_launch(void* const* d_in, const int* in_sizes, int n_in,
                              void* d_out, int out_size, void* d_ws, size_t ws_size,
                              hipStream_t stream) {
  const int* x = (const int*)d_in[0];
  const float* tok = (const float*)d_in[1];
  const float* pos = (const float*)d_in[2];
  const float* Wq = (const float*)d_in[3];
  const float* Wk = (const float*)d_in[4];
  const float* Wv = (const float*)d_in[5];
  const float* Wproj = (const float*)d_in[6];
  const float* bproj = (const float*)d_in[7];
  const float* ln1g = (const float*)d_in[8];
  const float* ln1b = (const float*)d_in[9];
  const float* ln2g = (const float*)d_in[10];
  const float* ln2b = (const float*)d_in[11];
  const float* W1 = (const float*)d_in[12];
  const float* b1 = (const float*)d_in[13];
  const float* W2 = (const float*)d_in[14];
  const float* b2 = (const float*)d_in[15];
  const float* lnfg = (const float*)d_in[16];
  const float* lnfb = (const float*)d_in[17];
  const float* Wout = (const float*)d_in[18];
  const float* bout = (const float*)d_in[19];
  float* out = (float*)d_out;

  // workspace layout
  char* ws = (char*)d_ws;
  size_t off = 0;
  auto alloc = [&](size_t bytes) { char* p = ws + off; off += (bytes + 255) & ~(size_t)255; return p; };
  uint16_t* wqkvT = (uint16_t*)alloc((size_t)Lx * 3 * D * D * 2);  // [L][3*D][D]
  uint16_t* wpT = (uint16_t*)alloc((size_t)Lx * D * D * 2);
  uint16_t* w1T = (uint16_t*)alloc((size_t)Lx * D * DFF * 2);
  uint16_t* w2T = (uint16_t*)alloc((size_t)Lx * D * DFF * 2);
  float* h = (float*)alloc((size_t)BT * D * 4);
  uint16_t* z = (uint16_t*)alloc((size_t)BT * D * 2);
  uint16_t* qkv = (uint16_t*)alloc((size_t)3 * QSZ * 2);  // q | k | v^T contiguous
  uint16_t* Sb = (uint16_t*)alloc((size_t)Bz * H * T * T * 2);
  uint16_t* o = (uint16_t*)alloc((size_t)BT * D * 2);
  uint16_t* a1 = (uint16_t*)alloc((size_t)BT * DFF * 2);
  (void)ws_size; (void)in_sizes; (void)n_in; (void)out_size;

  uint16_t* q = qkv;
  uint16_t* kb = qkv + QSZ;
  uint16_t* vt = qkv + 2 * QSZ;

  dim3 tb(32, 8);
  // weights -> bf16 B^T layout. wqkvT rows: [0,1024)=q, [1024,2048)=k, [2048,3072)=v
  transpose_cast_kernel<<<dim3(HS / 32, D / 32, Lx * H), tb, 0, stream>>>(
      Wq, wqkvT, D, HS, 3L * D * D, (long)HS * D, H);
  transpose_cast_kernel<<<dim3(HS / 32, D / 32, Lx * H), tb, 0, stream>>>(
      Wk, wqkvT + (long)D * D, D, HS, 3L * D * D, (long)HS * D, H);
  transpose_cast_kernel<<<dim3(HS / 32, D / 32, Lx * H), tb, 0, stream>>>(
      Wv, wqkvT + 2L * D * D, D, HS, 3L * D * D, (long)HS * D, H);
  transpose_cast_kernel<<<dim3(D / 32, D / 32, Lx), tb, 0, stream>>>(
      Wproj, wpT, D, D, (long)D * D, 0, 1);
  transpose_cast_kernel<<<dim3(DFF / 32, D / 32, Lx), tb, 0, stream>>>(
      W1, w1T, D, DFF, (long)D * DFF, 0, 1);
  transpose_cast_kernel<<<dim3(D / 32, DFF / 32, Lx), tb, 0, stream>>>(
      W2, w2T, DFF, D, (long)D * DFF, 0, 1);

  embed_kernel<<<BT, 256, 0, stream>>>(x, tok, pos, h);

  for (int l = 0; l < Lx; l++) {
    const uint16_t* wqkv_l = wqkvT + (size_t)l * 3 * D * D;
    const uint16_t* wp_l = wpT + (size_t)l * D * D;
    const uint16_t* w1_l = w1T + (size_t)l * D * DFF;
    const uint16_t* w2_l = w2T + (size_t)l * D * DFF;

    ln_kernel<true><<<BT, 256, 0, stream>>>(h, ln1g + l * D, ln1b + l * D, z);

    // fused QKV: [8192,1024] x [3072,1024]^T
    gemm_kernel<128, 128, 2, 2, MQKV><<<dim3(BT / 128, 3 * D / 128, 1), 256, 0, stream>>>(
        z, wqkv_l, BT, 3 * D, D, D, D, 0, 0, 0, nullptr, qkv);

    // S = q @ k^T per (b,h): M=N=512, K=64
    gemm_kernel<128, 128, 2, 2, MBF><<<dim3(T / 128, T / 128, Bz * H), 256, 0, stream>>>(
        q, kb, T, T, HS, HS, HS, (long)T * HS, (long)T * HS, (long)T * T, nullptr, Sb);

    softmax_kernel<<<Bz * H * T / 4, 256, 0, stream>>>(Sb);

    // O = P @ V : M=512, N=64, K=512
    gemm_kernel<128, 64, 4, 1, MO><<<dim3(T / 128, 1, Bz * H), 256, 0, stream>>>(
        Sb, vt, T, HS, T, T, T, (long)T * T, (long)HS * T, 0, nullptr, o);

    // h += o @ Wproj + bproj   (split-K=2, atomic)
    gemm_kernel<128, 128, 2, 2, MATOMIC><<<dim3(BT / 128, D / 128, 2), 256, 0, stream>>>(
        o, wp_l, BT, D, D / 2, D, D, 0, 0, 0, bproj + l * D, h);

    ln_kernel<true><<<BT, 256, 0, stream>>>(h, ln2g + l * D, ln2b + l * D, z);

    // a1 = gelu(z @ W1 + b1)
    gemm_kernel<128, 128, 2, 2, MGELU><<<dim3(BT / 128, DFF / 128, 1), 256, 0, stream>>>(
        z, w1_l, BT, DFF, D, D, D, 0, 0, 0, b1 + l * DFF, a1);

    // h += a1 @ W2 + b2   (split-K=2, atomic)
    gemm_kernel<128, 128, 2, 2, MATOMIC><<<dim3(BT / 128, D / 128, 2), 256, 0, stream>>>(
        a1, w2_l, BT, D, DFF / 2, DFF, DFF, 0, 0, 0, b2 + l * D, h);
  }

  // final LN in-place (fp32), then logits
  ln_kernel<false><<<BT, 256, 0, stream>>>(h, lnfg, lnfb, h);
  logits_init<<<1, 64, 0, stream>>>(bout, out);
  logits_kernel<<<dim3(64, Bz, NCn), 256, 0, stream>>>(h, Wout, out);
}

// Round 3
// 2514.445 us; speedup vs baseline: 1.1548x; 1.0305x over previous
//
#include <hip/hip_runtime.h>
#include <math.h>
#include <stdint.h>

#define DEV __device__ __forceinline__

// ---------------- problem constants ----------------
constexpr int Bz = 16, T = 512, D = 1024, H = 16, HS = 64, Lx = 4, DFF = 4096, NCn = 3;
constexpr int BT = Bz * T;  // 8192
constexpr long QSZ = (long)Bz * H * T * HS;  // elements per q/k/v tensor

typedef __attribute__((ext_vector_type(8))) short v8s;   // 8 x bf16 (4 VGPRs)
typedef __attribute__((ext_vector_type(4))) float v4f;   // MFMA accum

// ---------------- helpers ----------------
DEV uint16_t f2bf(float f) {            // round-to-nearest-even fp32 -> bf16
  uint32_t u = __float_as_uint(f);
  u += 0x7fff + ((u >> 16) & 1);
  return (uint16_t)(u >> 16);
}

DEV void async_copy16(const void* g, void* l) {
  // LDS base must be wave-uniform; HW deposits at base + lane*16
  __builtin_amdgcn_global_load_lds(
      (const __attribute__((address_space(1))) uint32_t*)g,
      (__attribute__((address_space(3))) uint32_t*)l, 16, 0, 0);
}

// ---- transpose + cast: in fp32 [R,C] batched z -> out bf16 [C,R] at (z/zdiv)*s1+(z%zdiv)*s2
__global__ void transpose_cast_kernel(const float* __restrict__ in, uint16_t* __restrict__ out,
                                      int R, int C, long s1, long s2, int zdiv) {
  __shared__ float tile[32][33];
  int zz = blockIdx.z;
  in += (long)zz * R * C;
  out += (long)(zz / zdiv) * s1 + (long)(zz % zdiv) * s2;
  int c0 = blockIdx.x * 32, r0 = blockIdx.y * 32;
  int tx = threadIdx.x, ty = threadIdx.y;  // 32 x 8
  for (int i = 0; i < 32; i += 8)
    tile[ty + i][tx] = in[(long)(r0 + ty + i) * C + (c0 + tx)];
  __syncthreads();
  for (int i = 0; i < 32; i += 8)
    out[(long)(c0 + ty + i) * R + (r0 + tx)] = f2bf(tile[tx][ty + i]);
}

// ---------------- embedding: h[b,t,:] = tok[x[b,t],:] + pos[t,:] ----------------
__global__ void embed_kernel(const int* __restrict__ x, const float* __restrict__ tok,
                             const float* __restrict__ pos, float* __restrict__ h) {
  int row = blockIdx.x;              // b*T + t
  int t = row & (T - 1);
  int id = x[row];
  const float4* tr = (const float4*)(tok + (long)id * D);
  const float4* pr = (const float4*)(pos + (long)t * D);
  float4* hr = (float4*)(h + (long)row * D);
  int i = threadIdx.x;               // 256 threads * 4 floats = 1024
  float4 a = tr[i], b = pr[i];
  hr[i] = make_float4(a.x + b.x, a.y + b.y, a.z + b.z, a.w + b.w);
}

// ---------------- layernorm over D=1024; one block per row ----------------
template <bool OUT_BF16>
__global__ void ln_kernel(const float* __restrict__ in, const float* __restrict__ g,
                          const float* __restrict__ b, void* __restrict__ out) {
  int row = blockIdx.x;
  int i = threadIdx.x;  // 256
  const float4* xr = (const float4*)(in + (long)row * D);
  float4 v = xr[i];
  float s = v.x + v.y + v.z + v.w;
  float s2 = v.x * v.x + v.y * v.y + v.z * v.z + v.w * v.w;
  for (int off = 32; off; off >>= 1) { s += __shfl_down(s, off); s2 += __shfl_down(s2, off); }
  __shared__ float sh1[4], sh2[4];
  int wid = i >> 6, lane = i & 63;
  if (lane == 0) { sh1[wid] = s; sh2[wid] = s2; }
  __syncthreads();
  s = sh1[0] + sh1[1] + sh1[2] + sh1[3];
  s2 = sh2[0] + sh2[1] + sh2[2] + sh2[3];
  float mu = s * (1.0f / D);
  float rstd = rsqrtf(s2 * (1.0f / D) - mu * mu + 1e-5f);
  float4 gv = ((const float4*)g)[i];
  float4 bv = ((const float4*)b)[i];
  float o0 = (v.x - mu) * rstd * gv.x + bv.x;
  float o1 = (v.y - mu) * rstd * gv.y + bv.y;
  float o2 = (v.z - mu) * rstd * gv.z + bv.z;
  float o3 = (v.w - mu) * rstd * gv.w + bv.w;
  if constexpr (OUT_BF16) {
    uint16_t* orow = (uint16_t*)out + (long)row * D;
    orow[4 * i + 0] = f2bf(o0); orow[4 * i + 1] = f2bf(o1);
    orow[4 * i + 2] = f2bf(o2); orow[4 * i + 3] = f2bf(o3);
  } else {
    ((float4*)((float*)out + (long)row * D))[i] = make_float4(o0, o1, o2, o3);
  }
}

// ---------- in-place scaled softmax: one wave per row of 512 bf16 (no LDS/barriers) ----------
__global__ void softmax_kernel(uint16_t* __restrict__ S) {
  int wid = threadIdx.x >> 6, lane = threadIdx.x & 63;
  long row = (long)blockIdx.x * 4 + wid;
  uint4* p = (uint4*)(S + row * T) + lane;   // 8 bf16 per lane
  uint4 u = *p;
  uint32_t w[4] = {u.x, u.y, u.z, u.w};
  float lo[4], hi[4];
  float m = -1e30f;
#pragma unroll
  for (int i = 0; i < 4; i++) {
    lo[i] = __uint_as_float(w[i] << 16) * 0.125f;          // * HS^-0.5
    hi[i] = __uint_as_float(w[i] & 0xffff0000u) * 0.125f;
    m = fmaxf(m, fmaxf(lo[i], hi[i]));
  }
  for (int off = 32; off; off >>= 1) m = fmaxf(m, __shfl_xor(m, off));
  float s = 0.f;
#pragma unroll
  for (int i = 0; i < 4; i++) {
    lo[i] = expf(lo[i] - m); hi[i] = expf(hi[i] - m);
    s += lo[i] + hi[i];
  }
  for (int off = 32; off; off >>= 1) s += __shfl_xor(s, off);
  float inv = 1.0f / s;
  uint4 o;
  uint32_t* ow = (uint32_t*)&o;
#pragma unroll
  for (int i = 0; i < 4; i++)
    ow[i] = (uint32_t)f2bf(lo[i] * inv) | ((uint32_t)f2bf(hi[i] * inv) << 16);
  *p = o;
}

// ---------------- the MFMA GEMM ----------------
// C[M,N] = A[M,K] * Bt[N,K]^T ; bf16, fp32 accum. Grid: x = M-tiles (fastest ->
// column-major traversal: XCD c owns rows ≡ c mod 8, B-stripe stays hot in its L2).
// BK = 64 staged as TWO 32-wide panels: 32 MFMA/wave between barrier pairs
// (halves barrier-drain count vs BK=32; LDS 32 KB for 128x128 tile).
// MATOMIC: blockIdx.z = K-split index, K = chunk length, lda/ldb = true leading dims.
enum { MQKV = 0, MBF = 1, MO = 2, MATOMIC = 3, MGELU = 4 };

template <int BM, int BN, int WGM, int WGN, int MODE>
__global__ void gemm_kernel(const uint16_t* __restrict__ A, const uint16_t* __restrict__ Bt,
                            int M, int N, int K, int lda, int ldb,
                            long strideA, long strideB, long strideC,
                            const float* __restrict__ bias, void* __restrict__ Cout) {
  constexpr int WM = BM / WGM, WN = BN / WGN;
  constexpr int TM = WM / 16, TN = WN / 16;
  __shared__ __align__(16) uint16_t As[2][BM * 32];  // two k-panels of 32
  __shared__ __align__(16) uint16_t Bs[2][BN * 32];
  int kz = 0, batch = 0;
  if constexpr (MODE == MATOMIC) kz = blockIdx.z; else batch = blockIdx.z;
  A += (long)batch * strideA;
  Bt += (long)batch * strideB;
  const int kb0 = kz * K;
  int bm0 = blockIdx.x * BM, bn0 = blockIdx.y * BN;
  int tid = threadIdx.x, wid = tid >> 6, lane = tid & 63;
  int wm = wid / WGN, wn = wid % WGN;
  v4f acc[TM][TN] = {};

  // staging: lane quad permuted (XOR swizzle) on the GLOBAL side; LDS dst stays lane*16
  const int laneRow = lane >> 2;                          // 16 rows per 1 KiB chunk
  const int laneB = ((lane & 3) ^ ((laneRow >> 1) & 3)) * 16;
  // fragment read: same XOR applied -> 2 lanes/bank-quad (free; verified 0 conflicts)
  const int rl = lane & 15;
  const int cx16 = (rl * 4 + ((lane >> 4) ^ ((rl >> 1) & 3))) * 16;  // byte offset in 1 KiB block

  for (int k0 = kb0; k0 < kb0 + K; k0 += 64) {
    __syncthreads();  // previous iter done reading LDS
#pragma unroll
    for (int p = 0; p < 2; p++) {
      for (int c = wid; c < BM / 16; c += 4) {
        int row = bm0 + c * 16 + laneRow;
        async_copy16((const char*)(A + (long)row * lda + k0 + p * 32) + laneB,
                     (char*)As[p] + c * 1024);
      }
      for (int c = wid; c < BN / 16; c += 4) {
        int col = bn0 + c * 16 + laneRow;
        async_copy16((const char*)(Bt + (long)col * ldb + k0 + p * 32) + laneB,
                     (char*)Bs[p] + c * 1024);
      }
    }
    __syncthreads();  // drains vmcnt -> staged tiles visible

#pragma unroll
    for (int p = 0; p < 2; p++) {
      v8s af[TM], bfr[TN];
#pragma unroll
      for (int i = 0; i < TM; i++)
        af[i] = *(const v8s*)((const char*)As[p] + (wm * (WM / 16) + i) * 1024 + cx16);
#pragma unroll
      for (int j = 0; j < TN; j++)
        bfr[j] = *(const v8s*)((const char*)Bs[p] + (wn * (WN / 16) + j) * 1024 + cx16);
#pragma unroll
      for (int i = 0; i < TM; i++)
#pragma unroll
        for (int j = 0; j < TN; j++)
          acc[i][j] = __builtin_amdgcn_mfma_f32_16x16x32_bf16(af[i], bfr[j], acc[i][j], 0, 0, 0);
    }
  }

  // epilogue: C/D layout col=lane&15, row=(lane>>4)*4+r
#pragma unroll
  for (int i = 0; i < TM; i++) {
    int row0 = bm0 + wm * WM + i * 16 + (lane >> 4) * 4;
#pragma unroll
    for (int j = 0; j < TN; j++) {
      int col = bn0 + wn * WN + j * 16 + (lane & 15);
#pragma unroll
      for (int r = 0; r < 4; r++) {
        int row = row0 + r;
        float val = acc[i][j][r];
        if constexpr (MODE == MQKV) {          // fused qkv scatter
          int sel = col >> 10, c = col & 1023;
          int hh = c >> 6, e = c & 63;
          int b = row >> 9, t = row & 511;
          long idx = (sel < 2) ? (((long)(b * H + hh) * T + t) * HS + e)
                               : (((long)(b * H + hh) * HS + e) * T + t);  // v transposed
          ((uint16_t*)Cout)[(long)sel * QSZ + idx] = f2bf(val);
        } else if constexpr (MODE == MBF) {    // plain bf16, batched (scores)
          ((uint16_t*)Cout)[(long)batch * strideC + (long)row * N + col] = f2bf(val);
        } else if constexpr (MODE == MO) {     // attn out: [b,t,h,e]; batch=b*H+h
          int b = batch >> 4, hh = batch & 15;
          ((uint16_t*)Cout)[((long)(b * T + row) * H + hh) * HS + col] = f2bf(val);
        } else if constexpr (MODE == MATOMIC) {  // h += partial (+bias once)
          float add = val + ((kz == 0) ? bias[col] : 0.f);
          atomicAdd(&((float*)Cout)[(long)row * N + col], add);
        } else if constexpr (MODE == MGELU) {  // bf16 gelu(acc + bias)
          float xg = val + bias[col];
          float gl = 0.5f * xg * (1.0f + erff(xg * 0.70710678118f));
          ((uint16_t*)Cout)[(long)row * N + col] = f2bf(gl);
        }
      }
    }
  }
}

// ---------------- logits: out[b,c] = bout[c] + sum_i h[b,i] * Wout[i,c] ----------------
__global__ void logits_init(const float* __restrict__ bout, float* __restrict__ out) {
  int i = threadIdx.x;
  if (i < Bz * NCn) out[i] = bout[i % NCn];
}
__global__ void logits_kernel(const float* __restrict__ hf, const float* __restrict__ Wout,
                              float* __restrict__ out) {
  int b = blockIdx.y, c = blockIdx.z;
  long base = (long)blockIdx.x * 8192;  // T*D / 64 chunks
  const float* hv = hf + (long)b * T * D + base;
  const float* w = Wout + base * NCn + c;
  float s = 0.f;
  for (int i = threadIdx.x; i < 8192; i += 256) s += hv[i] * w[(long)i * NCn];
  for (int off = 32; off; off >>= 1) s += __shfl_down(s, off);
  __shared__ float sh[4];
  int wid = threadIdx.x >> 6, lane = threadIdx.x & 63;
  if (lane == 0) sh[wid] = s;
  __syncthreads();
  if (threadIdx.x == 0) atomicAdd(out + b * NCn + c, sh[0] + sh[1] + sh[2] + sh[3]);
}

// ---------------- host ----------------
extern "C" void kernel_launch(void* const* d_in, const int* in_sizes, int n_in,
                              void* d_out, int out_size, void* d_ws, size_t ws_size,
                              hipStream_t stream) {
  const int* x = (const int*)d_in[0];
  const float* tok = (const float*)d_in[1];
  const float* pos = (const float*)d_in[2];
  const float* Wq = (const float*)d_in[3];
  const float* Wk = (const float*)d_in[4];
  const float* Wv = (const float*)d_in[5];
  const float* Wproj = (const float*)d_in[6];
  const float* bproj = (const float*)d_in[7];
  const float* ln1g = (const float*)d_in[8];
  const float* ln1b = (const float*)d_in[9];
  const float* ln2g = (const float*)d_in[10];
  const float* ln2b = (const float*)d_in[11];
  const float* W1 = (const float*)d_in[12];
  const float* b1 = (const float*)d_in[13];
  const float* W2 = (const float*)d_in[14];
  const float* b2 = (const float*)d_in[15];
  const float* lnfg = (const float*)d_in[16];
  const float* lnfb = (const float*)d_in[17];
  const float* Wout = (const float*)d_in[18];
  const float* bout = (const float*)d_in[19];
  float* out = (float*)d_out;

  // workspace layout
  char* ws = (char*)d_ws;
  size_t off = 0;
  auto alloc = [&](size_t bytes) { char* p = ws + off; off += (bytes + 255) & ~(size_t)255; return p; };
  uint16_t* wqkvT = (uint16_t*)alloc((size_t)Lx * 3 * D * D * 2);  // [L][3*D][D]
  uint16_t* wpT = (uint16_t*)alloc((size_t)Lx * D * D * 2);
  uint16_t* w1T = (uint16_t*)alloc((size_t)Lx * D * DFF * 2);
  uint16_t* w2T = (uint16_t*)alloc((size_t)Lx * D * DFF * 2);
  float* h = (float*)alloc((size_t)BT * D * 4);
  uint16_t* z = (uint16_t*)alloc((size_t)BT * D * 2);
  uint16_t* qkv = (uint16_t*)alloc((size_t)3 * QSZ * 2);  // q | k | v^T contiguous
  uint16_t* Sb = (uint16_t*)alloc((size_t)Bz * H * T * T * 2);
  uint16_t* o = (uint16_t*)alloc((size_t)BT * D * 2);
  uint16_t* a1 = (uint16_t*)alloc((size_t)BT * DFF * 2);
  (void)ws_size; (void)in_sizes; (void)n_in; (void)out_size;

  uint16_t* q = qkv;
  uint16_t* kb = qkv + QSZ;
  uint16_t* vt = qkv + 2 * QSZ;

  dim3 tb(32, 8);
  // weights -> bf16 B^T layout. wqkvT rows: [0,1024)=q, [1024,2048)=k, [2048,3072)=v
  transpose_cast_kernel<<<dim3(HS / 32, D / 32, Lx * H), tb, 0, stream>>>(
      Wq, wqkvT, D, HS, 3L * D * D, (long)HS * D, H);
  transpose_cast_kernel<<<dim3(HS / 32, D / 32, Lx * H), tb, 0, stream>>>(
      Wk, wqkvT + (long)D * D, D, HS, 3L * D * D, (long)HS * D, H);
  transpose_cast_kernel<<<dim3(HS / 32, D / 32, Lx * H), tb, 0, stream>>>(
      Wv, wqkvT + 2L * D * D, D, HS, 3L * D * D, (long)HS * D, H);
  transpose_cast_kernel<<<dim3(D / 32, D / 32, Lx), tb, 0, stream>>>(
      Wproj, wpT, D, D, (long)D * D, 0, 1);
  transpose_cast_kernel<<<dim3(DFF / 32, D / 32, Lx), tb, 0, stream>>>(
      W1, w1T, D, DFF, (long)D * DFF, 0, 1);
  transpose_cast_kernel<<<dim3(D / 32, DFF / 32, Lx), tb, 0, stream>>>(
      W2, w2T, DFF, D, (long)D * DFF, 0, 1);

  embed_kernel<<<BT, 256, 0, stream>>>(x, tok, pos, h);

  for (int l = 0; l < Lx; l++) {
    const uint16_t* wqkv_l = wqkvT + (size_t)l * 3 * D * D;
    const uint16_t* wp_l = wpT + (size_t)l * D * D;
    const uint16_t* w1_l = w1T + (size_t)l * D * DFF;
    const uint16_t* w2_l = w2T + (size_t)l * D * DFF;

    ln_kernel<true><<<BT, 256, 0, stream>>>(h, ln1g + l * D, ln1b + l * D, z);

    // fused QKV: [8192,1024] x [3072,1024]^T
    gemm_kernel<128, 128, 2, 2, MQKV><<<dim3(BT / 128, 3 * D / 128, 1), 256, 0, stream>>>(
        z, wqkv_l, BT, 3 * D, D, D, D, 0, 0, 0, nullptr, qkv);

    // S = q @ k^T per (b,h): M=N=512, K=64 -> single K-iteration
    gemm_kernel<128, 128, 2, 2, MBF><<<dim3(T / 128, T / 128, Bz * H), 256, 0, stream>>>(
        q, kb, T, T, HS, HS, HS, (long)T * HS, (long)T * HS, (long)T * T, nullptr, Sb);

    softmax_kernel<<<Bz * H * T / 4, 256, 0, stream>>>(Sb);

    // O = P @ V : M=512, N=64, K=512
    gemm_kernel<128, 64, 4, 1, MO><<<dim3(T / 128, 1, Bz * H), 256, 0, stream>>>(
        Sb, vt, T, HS, T, T, T, (long)T * T, (long)HS * T, 0, nullptr, o);

    // h += o @ Wproj + bproj   (split-K=2, atomic)
    gemm_kernel<128, 128, 2, 2, MATOMIC><<<dim3(BT / 128, D / 128, 2), 256, 0, stream>>>(
        o, wp_l, BT, D, D / 2, D, D, 0, 0, 0, bproj + l * D, h);

    ln_kernel<true><<<BT, 256, 0, stream>>>(h, ln2g + l * D, ln2b + l * D, z);

    // a1 = gelu(z @ W1 + b1)
    gemm_kernel<128, 128, 2, 2, MGELU><<<dim3(BT / 128, DFF / 128, 1), 256, 0, stream>>>(
        z, w1_l, BT, DFF, D, D, D, 0, 0, 0, b1 + l * DFF, a1);

    // h += a1 @ W2 + b2   (split-K=2, atomic)
    gemm_kernel<128, 128, 2, 2, MATOMIC><<<dim3(BT / 128, D / 128, 2), 256, 0, stream>>>(
        a1, w2_l, BT, D, DFF / 2, DFF, DFF, 0, 0, 0, b2 + l * D, h);
  }

  // final LN in-place (fp32), then logits
  ln_kernel<false><<<BT, 256, 0, stream>>>(h, lnfg, lnfb, h);
  logits_init<<<1, 64, 0, stream>>>(bout, out);
  logits_kernel<<<dim3(64, Bz, NCn), 256, 0, stream>>>(h, Wout, out);
}